// Round 1
// baseline (280.855 us; speedup 1.0000x reference)
//
#include <hip/hip_runtime.h>
#include <hip/hip_bf16.h>
#include <stdint.h>

#define B_ 2
#define S_ 2048
#define E_ 1024
#define H_ 16
#define D_ 64
#define LOG2E 1.4426950408889634f

typedef unsigned short ubf;
typedef __attribute__((ext_vector_type(8))) short bh8;   // 8 bf16 (4 VGPRs) MFMA A/B frag
typedef __attribute__((ext_vector_type(4))) float fx4;   // MFMA C/D frag

__device__ __forceinline__ ubf f2bf(float f) {
  unsigned u = __float_as_uint(f);
  unsigned r = (u + 0x7fffu + ((u >> 16) & 1u)) >> 16;  // RNE
  return (ubf)r;
}

__device__ __forceinline__ void gl_lds16(const void* g, void* l) {
  __builtin_amdgcn_global_load_lds(
      (const __attribute__((address_space(1))) void*)g,
      (__attribute__((address_space(3))) void*)l, 16, 0, 0);
}

// ---------------- prepass: fp32 -> bf16 convert of q/k/v (z selects array), zero flag
__global__ void cvt3(const float* __restrict__ q, const float* __restrict__ k,
                     const float* __restrict__ v, ubf* __restrict__ dst0,
                     int* __restrict__ flag) {
  if (blockIdx.x == 0 && blockIdx.z == 0 && threadIdx.x == 0) *flag = 0;
  const float* src = (blockIdx.z == 0) ? q : (blockIdx.z == 1) ? k : v;
  ubf* dst = dst0 + (size_t)blockIdx.z * (B_ * S_ * E_);
  int n4 = (B_ * S_ * E_) / 4;
  int stride = gridDim.x * blockDim.x;
  for (int j = blockIdx.x * blockDim.x + threadIdx.x; j < n4; j += stride) {
    float4 x = ((const float4*)src)[j];
    ushort4 o;
    o.x = f2bf(x.x); o.y = f2bf(x.y); o.z = f2bf(x.z); o.w = f2bf(x.w);
    ((ushort4*)dst)[j] = o;
  }
}

// ---------------- prepass: weight transpose+convert  Wt[n][k] = W[k][n] (bf16)
__global__ void wtrans4(const float* __restrict__ Wq, const float* __restrict__ Wk,
                        const float* __restrict__ Wv, const float* __restrict__ Wo,
                        ubf* __restrict__ Wt0) {
  __shared__ float t[32][33];
  int z = blockIdx.z;
  const float* W = (z == 0) ? Wq : (z == 1) ? Wk : (z == 2) ? Wv : Wo;
  ubf* Wt = Wt0 + (size_t)z * (E_ * E_);
  int kb = blockIdx.x, nb = blockIdx.y;
  int c = threadIdx.x & 31, r0 = threadIdx.x >> 5;
#pragma unroll
  for (int rr = 0; rr < 32; rr += 8)
    t[r0 + rr][c] = W[(size_t)(kb * 32 + r0 + rr) * E_ + nb * 32 + c];
  __syncthreads();
#pragma unroll
  for (int rr = 0; rr < 32; rr += 8)
    Wt[(size_t)(nb * 32 + r0 + rr) * E_ + kb * 32 + c] = f2bf(t[c][r0 + rr]);
}

// ---------------- prepass: does the mask contain any nonzero?
__global__ void maskscan(const float* __restrict__ m, int n4, int* __restrict__ flag) {
  int stride = gridDim.x * blockDim.x;
  int any = 0;
  for (int j = blockIdx.x * blockDim.x + threadIdx.x; j < n4; j += stride) {
    float4 x = ((const float4*)m)[j];
    any |= (x.x != 0.f) | (x.y != 0.f) | (x.z != 0.f) | (x.w != 0.f);
  }
  if (any) atomicOr(flag, 1);
}

// ---------------- GEMM: C[m][n] = sum_k A[m][k]*Bt[n][k], A/Bt bf16 row-major, K=1024
// MODE 0: Q proj  -> bf16 [B,H,S,D], (val+bias[n])*0.125
// MODE 1: K proj  -> bf16 [B,H,S,D], val+bias[n]
// MODE 2: V proj (A=Wv^T, B=Xv) -> bf16 [B,H,D,S], val+bias[m]
// MODE 3: final   -> fp32 [M][N], val+bias[n]
template <int MODE>
__global__ void __launch_bounds__(256)
gemm_bt(const ubf* __restrict__ A, const ubf* __restrict__ Bt,
        const float* __restrict__ bias, void* __restrict__ Cout, int M, int N) {
  constexpr int K = 1024;
  __shared__ ubf Asm[2][128 * 32];
  __shared__ ubf Bsm[2][128 * 32];
  const int tid = threadIdx.x;
  const int lane = tid & 63, w = tid >> 6;
  const int wm = w >> 1, wn = w & 1;
  const int bm = blockIdx.y, bn = blockIdx.x;
  const int g = lane >> 4, c15 = lane & 15;

  const fx4 FZ = {0.f, 0.f, 0.f, 0.f};
  fx4 acc[4][4];
#pragma unroll
  for (int m = 0; m < 4; m++)
#pragma unroll
    for (int n = 0; n < 4; n++) acc[m][n] = FZ;

  auto stage = [&](int buf, int k0) {
#pragma unroll
    for (int i = 0; i < 2; i++) {
      int s = i * 256 + tid;
      int row = s >> 2, cc = s & 3;
      int sc = cc ^ (row & 3);  // pre-swizzled global source (rule 21)
      gl_lds16(A + (size_t)(bm * 128 + row) * K + k0 + sc * 8,
               (char*)&Asm[buf][0] + (i * 256 + (tid & 192)) * 16);
      gl_lds16(Bt + (size_t)(bn * 128 + row) * K + k0 + sc * 8,
               (char*)&Bsm[buf][0] + (i * 256 + (tid & 192)) * 16);
    }
  };

  stage(0, 0);
  __syncthreads();
  for (int t = 0; t < K / 32; t++) {
    int cur = t & 1;
    if (t + 1 < K / 32) stage(cur ^ 1, (t + 1) * 32);
    bh8 a[4], b[4];
#pragma unroll
    for (int m = 0; m < 4; m++) {
      int row = wm * 64 + m * 16 + c15;
      int ch = g ^ (row & 3);
      a[m] = *(const bh8*)((const char*)&Asm[cur][0] + row * 64 + ch * 16);
    }
#pragma unroll
    for (int n = 0; n < 4; n++) {
      int row = wn * 64 + n * 16 + c15;
      int ch = g ^ (row & 3);
      b[n] = *(const bh8*)((const char*)&Bsm[cur][0] + row * 64 + ch * 16);
    }
#pragma unroll
    for (int m = 0; m < 4; m++)
#pragma unroll
      for (int n = 0; n < 4; n++)
        acc[m][n] = __builtin_amdgcn_mfma_f32_16x16x32_bf16(a[m], b[n], acc[m][n], 0, 0, 0);
    __syncthreads();
  }

  // epilogue; C/D layout: col=lane&15, row=(lane>>4)*4+reg  [m89]
#pragma unroll
  for (int m = 0; m < 4; m++) {
    int rbase = bm * 128 + wm * 64 + m * 16 + g * 4;
#pragma unroll
    for (int n = 0; n < 4; n++) {
      int col = bn * 128 + wn * 64 + n * 16 + c15;
#pragma unroll
      for (int r = 0; r < 4; r++) {
        int mrow = rbase + r;
        float val = acc[m][n][r];
        if constexpr (MODE == 0 || MODE == 1) {
          val = val + bias[col];
          if constexpr (MODE == 0) val *= 0.125f;  // fold 1/sqrt(D)
          int bb = mrow >> 11, ss = mrow & 2047, hh = col >> 6, dd = col & 63;
          ((ubf*)Cout)[((size_t)(bb * H_ + hh) * S_ + ss) * D_ + dd] = f2bf(val);
        } else if constexpr (MODE == 2) {
          val = val + bias[mrow];
          int bb = col >> 11, ss = col & 2047, hh = mrow >> 6, dd = mrow & 63;
          ((ubf*)Cout)[((size_t)(bb * H_ + hh) * D_ + dd) * S_ + ss] = f2bf(val);
        } else {
          ((float*)Cout)[(size_t)mrow * N + col] = val + bias[col];
        }
      }
    }
  }
}

// ---------------- flash attention: Q[B,H,S,D], K[B,H,S,D], V^T[B,H,D,S] -> AO[B,S,E] bf16
__global__ void __launch_bounds__(256)
flash(const ubf* __restrict__ Q, const ubf* __restrict__ Kh, const ubf* __restrict__ Vt,
      const float* __restrict__ mask, const int* __restrict__ flag, ubf* __restrict__ AO) {
  __shared__ ubf Ksm[2][64 * 64];
  __shared__ ubf Vsm[2][64 * 64];
  __shared__ ubf Psm[4][16 * 64];
  const int tid = threadIdx.x, lane = tid & 63, w = tid >> 6;
  const int g = lane >> 4, c15 = lane & 15;
  const int qb = blockIdx.x;   // q-tile (64 rows)
  const int bh = blockIdx.y;   // b*16+h
  const int b = bh >> 4, h = bh & 15;
  const int use_mask = *flag;

  // Q fragments in registers (row = c15 within this wave's 16 q-rows)
  const ubf* Qbase = Q + ((size_t)bh * S_ + qb * 64 + w * 16) * D_;
  bh8 aq[2];
#pragma unroll
  for (int kf = 0; kf < 2; kf++)
    aq[kf] = *(const bh8*)(Qbase + (size_t)c15 * D_ + kf * 32 + g * 8);

  const fx4 FZ = {0.f, 0.f, 0.f, 0.f};
  fx4 acc_o[4];
#pragma unroll
  for (int n = 0; n < 4; n++) acc_o[n] = FZ;
  float mrun[4], lrun[4];
#pragma unroll
  for (int r = 0; r < 4; r++) { mrun[r] = -3.0e38f; lrun[r] = 0.f; }

  const ubf* Kg = Kh + (size_t)bh * S_ * D_;
  const ubf* Vg = Vt + (size_t)bh * D_ * S_;

  auto stage = [&](int buf, int k0) {
#pragma unroll
    for (int i = 0; i < 2; i++) {
      int s = i * 256 + tid;
      int row = s >> 3, cc = s & 7;
      int sc = cc ^ (row & 7);  // pre-swizzled source; read side applies same XOR
      gl_lds16(Kg + (size_t)(k0 + row) * D_ + sc * 8,
               (char*)&Ksm[buf][0] + (i * 256 + (tid & 192)) * 16);
      gl_lds16(Vg + (size_t)row * S_ + k0 + sc * 8,
               (char*)&Vsm[buf][0] + (i * 256 + (tid & 192)) * 16);
    }
  };

  stage(0, 0);
  __syncthreads();

  const float* mrow_base = mask + ((size_t)b * S_ + qb * 64 + w * 16) * S_;

  for (int t = 0; t < S_ / 64; t++) {
    int cur = t & 1;
    if (t + 1 < S_ / 64) stage(cur ^ 1, (t + 1) * 64);

    // ---- QK^T : scores[16 q][64 keys], Q pre-scaled by 1/8
    fx4 sc4[4];
#pragma unroll
    for (int n = 0; n < 4; n++) sc4[n] = FZ;
#pragma unroll
    for (int kf = 0; kf < 2; kf++) {
#pragma unroll
      for (int n = 0; n < 4; n++) {
        int krow = n * 16 + c15;
        int ch = (g + 4 * kf) ^ (c15 & 7);
        bh8 bk = *(const bh8*)((const char*)&Ksm[cur][0] + krow * 128 + ch * 16);
        sc4[n] = __builtin_amdgcn_mfma_f32_16x16x32_bf16(aq[kf], bk, sc4[n], 0, 0, 0);
      }
    }
    if (use_mask) {
#pragma unroll
      for (int n = 0; n < 4; n++)
#pragma unroll
        for (int r = 0; r < 4; r++)
          sc4[n][r] += mrow_base[(size_t)(g * 4 + r) * S_ + t * 64 + n * 16 + c15] * (-10000.0f);
    }

    // ---- online softmax (wave-parallel: 16-lane group owns 4 rows)
    float al[4];
#pragma unroll
    for (int r = 0; r < 4; r++) {
      float x = fmaxf(fmaxf(sc4[0][r], sc4[1][r]), fmaxf(sc4[2][r], sc4[3][r]));
      x = fmaxf(x, __shfl_xor(x, 1));
      x = fmaxf(x, __shfl_xor(x, 2));
      x = fmaxf(x, __shfl_xor(x, 4));
      x = fmaxf(x, __shfl_xor(x, 8));
      float mn = fmaxf(mrun[r], x);
      al[r] = exp2f((mrun[r] - mn) * LOG2E);
      mrun[r] = mn;
    }
    float rs[4] = {0.f, 0.f, 0.f, 0.f};
#pragma unroll
    for (int n = 0; n < 4; n++)
#pragma unroll
      for (int r = 0; r < 4; r++) {
        float p = exp2f((sc4[n][r] - mrun[r]) * LOG2E);
        sc4[n][r] = p;
        rs[r] += p;
      }
#pragma unroll
    for (int r = 0; r < 4; r++) {
      rs[r] += __shfl_xor(rs[r], 1);
      rs[r] += __shfl_xor(rs[r], 2);
      rs[r] += __shfl_xor(rs[r], 4);
      rs[r] += __shfl_xor(rs[r], 8);
      lrun[r] = lrun[r] * al[r] + rs[r];
    }

    // ---- P -> LDS (bf16, swizzled), wave-private region
#pragma unroll
    for (int n = 0; n < 4; n++)
#pragma unroll
      for (int r = 0; r < 4; r++) {
        int prow = g * 4 + r;
        int colb = (n * 16 + c15) * 2;
        int swb = ((((colb >> 4) ^ (prow & 7)) << 4) | (colb & 15));
        *(ubf*)((char*)&Psm[w][0] + prow * 128 + swb) = f2bf(sc4[n][r]);
      }

    // ---- rescale O, then PV
#pragma unroll
    for (int n = 0; n < 4; n++)
#pragma unroll
      for (int r = 0; r < 4; r++) acc_o[n][r] *= al[r];

#pragma unroll
    for (int kf = 0; kf < 2; kf++) {
      int ch = (g + 4 * kf) ^ (c15 & 7);
      bh8 pa = *(const bh8*)((const char*)&Psm[w][0] + c15 * 128 + ch * 16);
#pragma unroll
      for (int n = 0; n < 4; n++) {
        int drow = n * 16 + c15;
        bh8 bv = *(const bh8*)((const char*)&Vsm[cur][0] + drow * 128 + ch * 16);
        acc_o[n] = __builtin_amdgcn_mfma_f32_16x16x32_bf16(pa, bv, acc_o[n], 0, 0, 0);
      }
    }
    __syncthreads();
  }

  // ---- epilogue: AO[b, s, h*64+d] = O / l
  int tok = qb * 64 + w * 16 + g * 4;
#pragma unroll
  for (int r = 0; r < 4; r++) {
    float inv = 1.0f / lrun[r];
#pragma unroll
    for (int n = 0; n < 4; n++) {
      int e = h * 64 + n * 16 + c15;
      AO[(size_t)(b * S_ + tok + r) * E_ + e] = f2bf(acc_o[n][r] * inv);
    }
  }
}

extern "C" void kernel_launch(void* const* d_in, const int* in_sizes, int n_in,
                              void* d_out, int out_size, void* d_ws, size_t ws_size,
                              hipStream_t stream) {
  (void)in_sizes; (void)n_in; (void)out_size; (void)ws_size;
  const float* q  = (const float*)d_in[0];
  const float* k  = (const float*)d_in[1];
  const float* v  = (const float*)d_in[2];
  const float* mask = (const float*)d_in[3];
  const float* Wq = (const float*)d_in[4];
  const float* bq = (const float*)d_in[5];
  const float* Wk = (const float*)d_in[6];
  const float* bk = (const float*)d_in[7];
  const float* Wv = (const float*)d_in[8];
  const float* bv = (const float*)d_in[9];
  const float* Wo = (const float*)d_in[10];
  const float* bo = (const float*)d_in[11];

  char* ws = (char*)d_ws;
  ubf* Xq  = (ubf*)(ws);                  // [4096,1024] bf16  8 MiB
  ubf* Xk  = (ubf*)(ws + 8388608);
  ubf* Xv  = (ubf*)(ws + 16777216);
  ubf* Wt0 = (ubf*)(ws + 25165824);       // Wq^T,Wk^T,Wv^T,Wo^T  4x2 MiB
  ubf* Qh  = (ubf*)(ws + 33554432);       // [B,H,S,D] bf16
  ubf* Kh  = (ubf*)(ws + 41943040);       // [B,H,S,D] bf16
  ubf* Vt  = (ubf*)(ws + 50331648);       // [B,H,D,S] bf16
  ubf* AO  = (ubf*)(ws + 58720256);       // [4096,1024] bf16
  int* flag = (int*)(ws + 67108864);

  ubf* Wqt = Wt0;
  ubf* Wkt = Wt0 + 1048576;
  ubf* Wvt = Wt0 + 2097152;
  ubf* Wot = Wt0 + 3145728;

  cvt3<<<dim3(512, 1, 3), 256, 0, stream>>>(q, k, v, Xq, flag);
  wtrans4<<<dim3(32, 32, 4), 256, 0, stream>>>(Wq, Wk, Wv, Wo, Wt0);
  maskscan<<<1024, 256, 0, stream>>>(mask, (B_ * S_ * S_) / 4, flag);

  gemm_bt<0><<<dim3(8, 32), 256, 0, stream>>>(Xq, Wqt, bq, Qh, 4096, 1024);
  gemm_bt<1><<<dim3(8, 32), 256, 0, stream>>>(Xk, Wkt, bk, Kh, 4096, 1024);
  gemm_bt<2><<<dim3(32, 8), 256, 0, stream>>>(Wvt, Xv, bv, Vt, 1024, 4096);

  flash<<<dim3(32, 32), 256, 0, stream>>>(Qh, Kh, Vt, mask, flag, AO);

  gemm_bt<3><<<dim3(8, 32), 256, 0, stream>>>(AO, Wot, bo, d_out, 4096, 1024);
}

// Round 2
// 182.269 us; speedup vs baseline: 1.5409x; 1.5409x over previous
//
#include <hip/hip_runtime.h>
#include <hip/hip_bf16.h>
#include <stdint.h>

#define B_ 2
#define S_ 2048
#define E_ 1024
#define H_ 16
#define D_ 64
#define LOG2E 1.4426950408889634f

typedef unsigned short ubf;
typedef __attribute__((ext_vector_type(8))) short bh8;    // 8 bf16 (4 VGPRs) MFMA A/B frag
typedef __attribute__((ext_vector_type(4))) float fx4;    // 16x16 C/D frag
typedef __attribute__((ext_vector_type(16))) float fx16;  // 32x32 C/D frag

__device__ __forceinline__ ubf f2bf(float f) {
  unsigned u = __float_as_uint(f);
  unsigned r = (u + 0x7fffu + ((u >> 16) & 1u)) >> 16;  // RNE
  return (ubf)r;
}

__device__ __forceinline__ unsigned cvtpk(float lo, float hi2) {
  unsigned r;
  asm("v_cvt_pk_bf16_f32 %0, %1, %2" : "=v"(r) : "v"(lo), "v"(hi2));
  return r;
}

__device__ __forceinline__ void gl_lds16(const void* g, void* l) {
  __builtin_amdgcn_global_load_lds(
      (const __attribute__((address_space(1))) void*)g,
      (__attribute__((address_space(3))) void*)l, 16, 0, 0);
}

// ---------------- prepass: fp32 -> bf16 convert of q/k/v (z selects array), zero flag
__global__ void cvt3(const float* __restrict__ q, const float* __restrict__ k,
                     const float* __restrict__ v, ubf* __restrict__ dst0,
                     int* __restrict__ flag) {
  if (blockIdx.x == 0 && blockIdx.z == 0 && threadIdx.x == 0) *flag = 0;
  const float* src = (blockIdx.z == 0) ? q : (blockIdx.z == 1) ? k : v;
  ubf* dst = dst0 + (size_t)blockIdx.z * (B_ * S_ * E_);
  int n4 = (B_ * S_ * E_) / 4;
  int stride = gridDim.x * blockDim.x;
  for (int j = blockIdx.x * blockDim.x + threadIdx.x; j < n4; j += stride) {
    float4 x = ((const float4*)src)[j];
    ushort4 o;
    o.x = f2bf(x.x); o.y = f2bf(x.y); o.z = f2bf(x.z); o.w = f2bf(x.w);
    ((ushort4*)dst)[j] = o;
  }
}

// ---------------- prepass: weight transpose+convert  Wt[n][k] = W[k][n] (bf16)
__global__ void wtrans4(const float* __restrict__ Wq, const float* __restrict__ Wk,
                        const float* __restrict__ Wv, const float* __restrict__ Wo,
                        ubf* __restrict__ Wt0) {
  __shared__ float t[32][33];
  int z = blockIdx.z;
  const float* W = (z == 0) ? Wq : (z == 1) ? Wk : (z == 2) ? Wv : Wo;
  ubf* Wt = Wt0 + (size_t)z * (E_ * E_);
  int kb = blockIdx.x, nb = blockIdx.y;
  int c = threadIdx.x & 31, r0 = threadIdx.x >> 5;
#pragma unroll
  for (int rr = 0; rr < 32; rr += 8)
    t[r0 + rr][c] = W[(size_t)(kb * 32 + r0 + rr) * E_ + nb * 32 + c];
  __syncthreads();
#pragma unroll
  for (int rr = 0; rr < 32; rr += 8)
    Wt[(size_t)(nb * 32 + r0 + rr) * E_ + kb * 32 + c] = f2bf(t[c][r0 + rr]);
}

// ---------------- prepass: does the mask contain any nonzero?
__global__ void maskscan(const float* __restrict__ m, int n4, int* __restrict__ flag) {
  int stride = gridDim.x * blockDim.x;
  int any = 0;
  for (int j = blockIdx.x * blockDim.x + threadIdx.x; j < n4; j += stride) {
    float4 x = ((const float4*)m)[j];
    any |= (x.x != 0.f) | (x.y != 0.f) | (x.z != 0.f) | (x.w != 0.f);
  }
  if (any) atomicOr(flag, 1);
}

// ================= fused QKV projection GEMM =================
// z=0: Q = Xq@Wq^T + bq, scaled 0.125 -> bf16 [B,H,S,D]
// z=1: K = Xk@Wk^T + bk                -> bf16 [B,H,S,D]
// z=2: V^T (A=Wv^T, B=Xv) + bv         -> bf16 [B,H,D,S]
__global__ void __launch_bounds__(256)
gemm_qkv(const ubf* __restrict__ X, const ubf* __restrict__ Wt,
         const float* __restrict__ bq, const float* __restrict__ bk,
         const float* __restrict__ bv, ubf* __restrict__ Out) {
  constexpr int K = 1024;
  __shared__ ubf Asm[2][128 * 32];
  __shared__ ubf Bsm[2][128 * 32];
  const int z = blockIdx.z;
  const ubf* A  = (z == 2) ? (Wt + 2u * 1048576u) : (X + (size_t)z * 4194304u);
  const ubf* Bt = (z == 2) ? (X + 2u * 4194304u) : (Wt + (size_t)z * 1048576u);
  const float* bias = (z == 0) ? bq : (z == 1) ? bk : bv;
  ubf* Cout = Out + (size_t)z * 4194304u;
  const int bm = (z == 2) ? blockIdx.y : blockIdx.x;  // z<2: 32 M-tiles; z=2: 8
  const int bn = (z == 2) ? blockIdx.x : blockIdx.y;  // z<2: 8 N-tiles;  z=2: 32

  const int tid = threadIdx.x;
  const int lane = tid & 63, w = tid >> 6;
  const int wm = w >> 1, wn = w & 1;
  const int g = lane >> 4, c15 = lane & 15;

  const fx4 FZ = {0.f, 0.f, 0.f, 0.f};
  fx4 acc[4][4];
#pragma unroll
  for (int m = 0; m < 4; m++)
#pragma unroll
    for (int n = 0; n < 4; n++) acc[m][n] = FZ;

  auto stage = [&](int buf, int k0) {
#pragma unroll
    for (int i = 0; i < 2; i++) {
      int s = i * 256 + tid;
      int row = s >> 2, cc = s & 3;
      int sc = cc ^ (row & 3);
      gl_lds16(A + (size_t)(bm * 128 + row) * K + k0 + sc * 8,
               (char*)&Asm[buf][0] + (i * 256 + (tid & 192)) * 16);
      gl_lds16(Bt + (size_t)(bn * 128 + row) * K + k0 + sc * 8,
               (char*)&Bsm[buf][0] + (i * 256 + (tid & 192)) * 16);
    }
  };

  stage(0, 0);
  __syncthreads();
  for (int t = 0; t < K / 32; t++) {
    int cur = t & 1;
    if (t + 1 < K / 32) stage(cur ^ 1, (t + 1) * 32);
    bh8 a[4], b[4];
#pragma unroll
    for (int m = 0; m < 4; m++) {
      int row = wm * 64 + m * 16 + c15;
      int ch = g ^ (row & 3);
      a[m] = *(const bh8*)((const char*)&Asm[cur][0] + row * 64 + ch * 16);
    }
#pragma unroll
    for (int n = 0; n < 4; n++) {
      int row = wn * 64 + n * 16 + c15;
      int ch = g ^ (row & 3);
      b[n] = *(const bh8*)((const char*)&Bsm[cur][0] + row * 64 + ch * 16);
    }
#pragma unroll
    for (int m = 0; m < 4; m++)
#pragma unroll
      for (int n = 0; n < 4; n++)
        acc[m][n] = __builtin_amdgcn_mfma_f32_16x16x32_bf16(a[m], b[n], acc[m][n], 0, 0, 0);
    __syncthreads();
  }

#pragma unroll
  for (int m = 0; m < 4; m++) {
    int rbase = bm * 128 + wm * 64 + m * 16 + g * 4;
#pragma unroll
    for (int n = 0; n < 4; n++) {
      int col = bn * 128 + wn * 64 + n * 16 + c15;
#pragma unroll
      for (int r = 0; r < 4; r++) {
        int mrow = rbase + r;
        float val = acc[m][n][r];
        if (z <= 1) {
          val = val + bias[col];
          if (z == 0) val *= 0.125f;  // fold 1/sqrt(D)
          int bb = mrow >> 11, ss = mrow & 2047, hh = col >> 6, dd = col & 63;
          Cout[((size_t)(bb * H_ + hh) * S_ + ss) * D_ + dd] = f2bf(val);
        } else {
          val = val + bias[mrow];
          int bb = col >> 11, ss = col & 2047, hh = mrow >> 6, dd = mrow & 63;
          Cout[((size_t)(bb * H_ + hh) * D_ + dd) * S_ + ss] = f2bf(val);
        }
      }
    }
  }
}

// ================= output GEMM: d_out = AO@Wo^T + bo (fp32) =================
__global__ void __launch_bounds__(256)
gemm_out(const ubf* __restrict__ A, const ubf* __restrict__ Bt,
         const float* __restrict__ bias, float* __restrict__ Cout, int N) {
  constexpr int K = 1024;
  __shared__ ubf Asm[2][128 * 32];
  __shared__ ubf Bsm[2][128 * 32];
  const int tid = threadIdx.x;
  const int lane = tid & 63, w = tid >> 6;
  const int wm = w >> 1, wn = w & 1;
  const int bm = blockIdx.y, bn = blockIdx.x;
  const int g = lane >> 4, c15 = lane & 15;

  const fx4 FZ = {0.f, 0.f, 0.f, 0.f};
  fx4 acc[4][4];
#pragma unroll
  for (int m = 0; m < 4; m++)
#pragma unroll
    for (int n = 0; n < 4; n++) acc[m][n] = FZ;

  auto stage = [&](int buf, int k0) {
#pragma unroll
    for (int i = 0; i < 2; i++) {
      int s = i * 256 + tid;
      int row = s >> 2, cc = s & 3;
      int sc = cc ^ (row & 3);
      gl_lds16(A + (size_t)(bm * 128 + row) * K + k0 + sc * 8,
               (char*)&Asm[buf][0] + (i * 256 + (tid & 192)) * 16);
      gl_lds16(Bt + (size_t)(bn * 128 + row) * K + k0 + sc * 8,
               (char*)&Bsm[buf][0] + (i * 256 + (tid & 192)) * 16);
    }
  };

  stage(0, 0);
  __syncthreads();
  for (int t = 0; t < K / 32; t++) {
    int cur = t & 1;
    if (t + 1 < K / 32) stage(cur ^ 1, (t + 1) * 32);
    bh8 a[4], b[4];
#pragma unroll
    for (int m = 0; m < 4; m++) {
      int row = wm * 64 + m * 16 + c15;
      int ch = g ^ (row & 3);
      a[m] = *(const bh8*)((const char*)&Asm[cur][0] + row * 64 + ch * 16);
    }
#pragma unroll
    for (int n = 0; n < 4; n++) {
      int row = wn * 64 + n * 16 + c15;
      int ch = g ^ (row & 3);
      b[n] = *(const bh8*)((const char*)&Bsm[cur][0] + row * 64 + ch * 16);
    }
#pragma unroll
    for (int m = 0; m < 4; m++)
#pragma unroll
      for (int n = 0; n < 4; n++)
        acc[m][n] = __builtin_amdgcn_mfma_f32_16x16x32_bf16(a[m], b[n], acc[m][n], 0, 0, 0);
    __syncthreads();
  }

#pragma unroll
  for (int m = 0; m < 4; m++) {
    int rbase = bm * 128 + wm * 64 + m * 16 + g * 4;
#pragma unroll
    for (int n = 0; n < 4; n++) {
      int col = bn * 128 + wn * 64 + n * 16 + c15;
#pragma unroll
      for (int r = 0; r < 4; r++)
        Cout[(size_t)(rbase + r) * N + col] = acc[m][n][r] + bias[col];
    }
  }
}

// ================= flash attention (8q-rows? no: 32 q-rows/wave, 32x32x16) =====
// Q[B,H,S,D] (pre-scaled), K[B,H,S,D], V^T[B,H,D,S] -> AO[B,S,E] bf16
// Swapped QK^T: sc = mfma(K, Q) => lane owns q = lane&31 for ALL its 32 scores.
// C/D map (32x32): col=lane&31, row=(r&3)+8*(r>>2)+4*(lane>>5)   [m74/m101]
#define ROWQ(r) (((r) & 3) + 8 * ((r) >> 2) + 4 * hi)

__global__ void __launch_bounds__(256)
flash(const ubf* __restrict__ Q, const ubf* __restrict__ Kh, const ubf* __restrict__ Vt,
      const float* __restrict__ mask, const int* __restrict__ flag, ubf* __restrict__ AO) {
  __shared__ ubf Ksm[2][64 * 64];
  __shared__ ubf Vsm[2][64 * 64];
  const int tid = threadIdx.x, lane = tid & 63, w = tid >> 6;
  const int l31 = lane & 31, hi = lane >> 5;
  const int qb = blockIdx.x;   // q-tile (128 rows/block, 32/wave)
  const int bh = blockIdx.y;   // b*16+h
  const int b = bh >> 4, h = bh & 15;
  const int use_mask = *flag;
  const int qg = qb * 128 + w * 32 + l31;

  // Q B-fragments in registers: B[k=d][col=q], lane: col=l31, d = kf*16 + hi*8 + j
  const ubf* Qrow = Q + ((size_t)bh * S_ + qg) * D_;
  bh8 q4[4];
#pragma unroll
  for (int kf = 0; kf < 4; kf++) q4[kf] = *(const bh8*)(Qrow + kf * 16 + hi * 8);

  fx16 acc0, acc1;
#pragma unroll
  for (int i = 0; i < 16; i++) { acc0[i] = 0.f; acc1[i] = 0.f; }
  float mrun = -3.0e38f, lrun = 0.f;

  const ubf* Kg = Kh + (size_t)bh * S_ * D_;
  const ubf* Vg = Vt + (size_t)bh * D_ * S_;

  auto stage = [&](int buf, int k0) {
#pragma unroll
    for (int i = 0; i < 2; i++) {
      int s = i * 256 + tid;
      int row = s >> 3, cc = s & 7;
      int sw = cc ^ (row & 7);  // pre-swizzled global source (rule 21)
      gl_lds16(Kg + (size_t)(k0 + row) * D_ + sw * 8,
               (char*)&Ksm[buf][0] + (i * 256 + (tid & 192)) * 16);
      gl_lds16(Vg + (size_t)row * S_ + k0 + sw * 8,
               (char*)&Vsm[buf][0] + (i * 256 + (tid & 192)) * 16);
    }
  };

  stage(0, 0);
  __syncthreads();

  for (int t = 0; t < S_ / 64; t++) {
    int cur = t & 1;
    if (t + 1 < S_ / 64) stage(cur ^ 1, (t + 1) * 64);

    // ---- QK^T: sc[n] = K-tile(n) x Q  -> scores[key][q], lane q = l31
    fx16 sc0, sc1;
#pragma unroll
    for (int i = 0; i < 16; i++) { sc0[i] = 0.f; sc1[i] = 0.f; }
#pragma unroll
    for (int kf = 0; kf < 4; kf++) {
      {
        int row = l31;  // n=0
        int ch = (2 * kf + hi) ^ (row & 7);
        bh8 ak = *(const bh8*)((const char*)&Ksm[cur][0] + row * 128 + ch * 16);
        sc0 = __builtin_amdgcn_mfma_f32_32x32x16_bf16(ak, q4[kf], sc0, 0, 0, 0);
      }
      {
        int row = 32 + l31;  // n=1
        int ch = (2 * kf + hi) ^ (row & 7);
        bh8 ak = *(const bh8*)((const char*)&Ksm[cur][0] + row * 128 + ch * 16);
        sc1 = __builtin_amdgcn_mfma_f32_32x32x16_bf16(ak, q4[kf], sc1, 0, 0, 0);
      }
    }

    if (use_mask) {
      const float* mq = mask + ((size_t)(b * S_ + qg)) * S_ + (size_t)t * 64;
#pragma unroll
      for (int r = 0; r < 16; r++) {
        sc0[r] += mq[ROWQ(r)] * (-10000.0f);
        sc1[r] += mq[32 + ROWQ(r)] * (-10000.0f);
      }
    }

    // ---- online softmax, lane-local row (q = l31); partner lane (^32) has other keys
    float pmax = sc0[0];
#pragma unroll
    for (int r = 0; r < 16; r++) pmax = fmaxf(pmax, fmaxf(sc0[r], sc1[r]));
    pmax = fmaxf(pmax, __shfl_xor(pmax, 32));

    if (__any(pmax - mrun > 8.0f)) {  // T13 defer-max
      float mnew = fmaxf(mrun, pmax);
      float al = exp2f((mrun - mnew) * LOG2E);
      lrun *= al;
#pragma unroll
      for (int r = 0; r < 16; r++) {
        float alr = __shfl(al, ROWQ(r));
        acc0[r] *= alr;
        acc1[r] *= alr;
      }
      mrun = mnew;
    }

    float rs = 0.f;
#pragma unroll
    for (int r = 0; r < 16; r++) {
      float p0 = exp2f((sc0[r] - mrun) * LOG2E);
      float p1 = exp2f((sc1[r] - mrun) * LOG2E);
      sc0[r] = p0; sc1[r] = p1;
      rs += p0 + p1;
    }
    rs += __shfl_xor(rs, 32);
    lrun += rs;

    // ---- pack P to bf16 pairs (T12): pk[n][i] = pack(p[n][2i], p[n][2i+1])
    unsigned pk0[8], pk1[8];
#pragma unroll
    for (int i = 0; i < 8; i++) {
      pk0[i] = cvtpk(sc0[2 * i], sc0[2 * i + 1]);
      pk1[i] = cvtpk(sc1[2 * i], sc1[2 * i + 1]);
    }

    // ---- PV: A = P (row=q=l31, k=key chunk hi*8), B = V; per kf exchange with ^32
#define PV_STEP(KF, PKN)                                                          \
    {                                                                             \
      const int o = 4 * ((KF) & 1);                                               \
      unsigned x00 = PKN[o], x01 = PKN[o + 1], x10 = PKN[o + 2], x11 = PKN[o + 3];\
      unsigned t0 = hi ? x00 : x10, t1 = hi ? x01 : x11;                          \
      unsigned r0 = (unsigned)__shfl_xor((int)t0, 32);                            \
      unsigned r1 = (unsigned)__shfl_xor((int)t1, 32);                            \
      unsigned wa[4];                                                             \
      wa[0] = hi ? r0 : x00; wa[1] = hi ? r1 : x01;                               \
      wa[2] = hi ? x10 : r0; wa[3] = hi ? x11 : r1;                               \
      bh8 pa = *(bh8*)wa;                                                         \
      {                                                                           \
        int row = l31;                                                            \
        int ch = (2 * (KF) + hi) ^ (row & 7);                                     \
        bh8 bv = *(const bh8*)((const char*)&Vsm[cur][0] + row * 128 + ch * 16);  \
        acc0 = __builtin_amdgcn_mfma_f32_32x32x16_bf16(pa, bv, acc0, 0, 0, 0);    \
      }                                                                           \
      {                                                                           \
        int row = 32 + l31;                                                       \
        int ch = (2 * (KF) + hi) ^ (row & 7);                                     \
        bh8 bv = *(const bh8*)((const char*)&Vsm[cur][0] + row * 128 + ch * 16);  \
        acc1 = __builtin_amdgcn_mfma_f32_32x32x16_bf16(pa, bv, acc1, 0, 0, 0);    \
      }                                                                           \
    }
    PV_STEP(0, pk0)
    PV_STEP(1, pk0)
    PV_STEP(2, pk1)
    PV_STEP(3, pk1)
#undef PV_STEP

    __syncthreads();
  }

  // ---- epilogue: AO[b, q, h*64+d] = O[q][d] / lrun(q)
#pragma unroll
  for (int r = 0; r < 16; r++) {
    int q2 = ROWQ(r);
    float linv = 1.0f / __shfl(lrun, q2);
    size_t base = ((size_t)(b * S_ + qb * 128 + w * 32 + q2)) * E_ + h * 64;
    AO[base + l31] = f2bf(acc0[r] * linv);
    AO[base + 32 + l31] = f2bf(acc1[r] * linv);
  }
}

extern "C" void kernel_launch(void* const* d_in, const int* in_sizes, int n_in,
                              void* d_out, int out_size, void* d_ws, size_t ws_size,
                              hipStream_t stream) {
  (void)in_sizes; (void)n_in; (void)out_size; (void)ws_size;
  const float* q  = (const float*)d_in[0];
  const float* k  = (const float*)d_in[1];
  const float* v  = (const float*)d_in[2];
  const float* mask = (const float*)d_in[3];
  const float* Wq = (const float*)d_in[4];
  const float* bq = (const float*)d_in[5];
  const float* Wk = (const float*)d_in[6];
  const float* bk = (const float*)d_in[7];
  const float* Wv = (const float*)d_in[8];
  const float* bv = (const float*)d_in[9];
  const float* Wo = (const float*)d_in[10];
  const float* bo = (const float*)d_in[11];

  char* ws = (char*)d_ws;
  ubf* X   = (ubf*)(ws);                  // Xq,Xk,Xv [4096,1024] bf16, 8 MiB each
  ubf* Wt0 = (ubf*)(ws + 25165824);       // Wq^T,Wk^T,Wv^T,Wo^T  4x2 MiB
  ubf* Qh  = (ubf*)(ws + 33554432);       // [B,H,S,D]; Kh,Vt follow at +8MiB each
  ubf* Kh  = (ubf*)(ws + 41943040);
  ubf* Vt  = (ubf*)(ws + 50331648);       // [B,H,D,S]
  ubf* AO  = (ubf*)(ws + 58720256);       // [4096,1024] bf16
  int* flag = (int*)(ws + 67108864);

  ubf* Wot = Wt0 + 3145728;

  cvt3<<<dim3(512, 1, 3), 256, 0, stream>>>(q, k, v, X, flag);
  wtrans4<<<dim3(32, 32, 4), 256, 0, stream>>>(Wq, Wk, Wv, Wo, Wt0);
  maskscan<<<1024, 256, 0, stream>>>(mask, (B_ * S_ * S_) / 4, flag);

  gemm_qkv<<<dim3(32, 8, 3), 256, 0, stream>>>(X, Wt0, bq, bk, bv, Qh);

  flash<<<dim3(16, 32), 256, 0, stream>>>(Qh, Kh, Vt, mask, flag, AO);

  gemm_out<<<dim3(8, 32), 256, 0, stream>>>(AO, Wot, bo, (float*)d_out, 1024);
}

// Round 3
// 179.438 us; speedup vs baseline: 1.5652x; 1.0158x over previous
//
#include <hip/hip_runtime.h>
#include <hip/hip_bf16.h>
#include <stdint.h>

#define B_ 2
#define S_ 2048
#define E_ 1024
#define H_ 16
#define D_ 64
#define LOG2E 1.4426950408889634f

typedef unsigned short ubf;
typedef __attribute__((ext_vector_type(8))) short bh8;    // 8 bf16 (4 VGPRs) MFMA A/B frag
typedef __attribute__((ext_vector_type(4))) float fx4;    // 16x16 C/D frag
typedef __attribute__((ext_vector_type(16))) float fx16;  // 32x32 C/D frag

__device__ __forceinline__ ubf f2bf(float f) {
  unsigned u = __float_as_uint(f);
  unsigned r = (u + 0x7fffu + ((u >> 16) & 1u)) >> 16;  // RNE
  return (ubf)r;
}
__device__ __forceinline__ float bf2f(ubf u) {
  return __uint_as_float(((unsigned)u) << 16);
}

__device__ __forceinline__ unsigned cvtpk(float lo, float hi2) {
  unsigned r;
  asm("v_cvt_pk_bf16_f32 %0, %1, %2" : "=v"(r) : "v"(lo), "v"(hi2));
  return r;
}

__device__ __forceinline__ void gl_lds16(const void* g, void* l) {
  __builtin_amdgcn_global_load_lds(
      (const __attribute__((address_space(1))) void*)g,
      (__attribute__((address_space(3))) void*)l, 16, 0, 0);
}

// ---------------- prepass: fp32 -> bf16 convert of q/k/v (z selects array), zero flag
__global__ void cvt3(const float* __restrict__ q, const float* __restrict__ k,
                     const float* __restrict__ v, ubf* __restrict__ dst0,
                     int* __restrict__ flag) {
  if (blockIdx.x == 0 && blockIdx.z == 0 && threadIdx.x == 0) *flag = 0;
  const float* src = (blockIdx.z == 0) ? q : (blockIdx.z == 1) ? k : v;
  ubf* dst = dst0 + (size_t)blockIdx.z * (B_ * S_ * E_);
  int n4 = (B_ * S_ * E_) / 4;
  int stride = gridDim.x * blockDim.x;
  for (int j = blockIdx.x * blockDim.x + threadIdx.x; j < n4; j += stride) {
    float4 x = ((const float4*)src)[j];
    ushort4 o;
    o.x = f2bf(x.x); o.y = f2bf(x.y); o.z = f2bf(x.z); o.w = f2bf(x.w);
    ((ushort4*)dst)[j] = o;
  }
}

// ---------------- prepass: weight transpose+convert  Wt[n][k] = W[k][n] (bf16)
__global__ void wtrans4(const float* __restrict__ Wq, const float* __restrict__ Wk,
                        const float* __restrict__ Wv, const float* __restrict__ Wo,
                        ubf* __restrict__ Wt0) {
  __shared__ float t[32][33];
  int z = blockIdx.z;
  const float* W = (z == 0) ? Wq : (z == 1) ? Wk : (z == 2) ? Wv : Wo;
  ubf* Wt = Wt0 + (size_t)z * (E_ * E_);
  int kb = blockIdx.x, nb = blockIdx.y;
  int c = threadIdx.x & 31, r0 = threadIdx.x >> 5;
#pragma unroll
  for (int rr = 0; rr < 32; rr += 8)
    t[r0 + rr][c] = W[(size_t)(kb * 32 + r0 + rr) * E_ + nb * 32 + c];
  __syncthreads();
#pragma unroll
  for (int rr = 0; rr < 32; rr += 8)
    Wt[(size_t)(nb * 32 + r0 + rr) * E_ + kb * 32 + c] = f2bf(t[c][r0 + rr]);
}

// ---------------- prepass: does the mask contain any nonzero?
__global__ void maskscan(const float* __restrict__ m, int n4, int* __restrict__ flag) {
  int stride = gridDim.x * blockDim.x;
  int any = 0;
  for (int j = blockIdx.x * blockDim.x + threadIdx.x; j < n4; j += stride) {
    float4 x = ((const float4*)m)[j];
    any |= (x.x != 0.f) | (x.y != 0.f) | (x.z != 0.f) | (x.w != 0.f);
  }
  if (any) atomicOr(flag, 1);
}

// ================= fused QKV projection GEMM =================
// z=0: Q = Xq@Wq^T + bq, scaled 0.125*LOG2E -> bf16 [B,H,S,D]  (log2-domain scores)
// z=1: K = Xk@Wk^T + bk                      -> bf16 [B,H,S,D]
// z=2: V^T (A=Wv^T, B=Xv) + bv               -> bf16 [B,H,D,S]
__global__ void __launch_bounds__(256)
gemm_qkv(const ubf* __restrict__ X, const ubf* __restrict__ Wt,
         const float* __restrict__ bq, const float* __restrict__ bk,
         const float* __restrict__ bv, ubf* __restrict__ Out) {
  constexpr int K = 1024;
  __shared__ ubf Asm[2][128 * 32];
  __shared__ ubf Bsm[2][128 * 32];
  const int z = blockIdx.z;
  const ubf* A  = (z == 2) ? (Wt + 2u * 1048576u) : (X + (size_t)z * 4194304u);
  const ubf* Bt = (z == 2) ? (X + 2u * 4194304u) : (Wt + (size_t)z * 1048576u);
  const float* bias = (z == 0) ? bq : (z == 1) ? bk : bv;
  ubf* Cout = Out + (size_t)z * 4194304u;
  const int bm = (z == 2) ? blockIdx.y : blockIdx.x;
  const int bn = (z == 2) ? blockIdx.x : blockIdx.y;

  const int tid = threadIdx.x;
  const int lane = tid & 63, w = tid >> 6;
  const int wm = w >> 1, wn = w & 1;
  const int g = lane >> 4, c15 = lane & 15;

  const fx4 FZ = {0.f, 0.f, 0.f, 0.f};
  fx4 acc[4][4];
#pragma unroll
  for (int m = 0; m < 4; m++)
#pragma unroll
    for (int n = 0; n < 4; n++) acc[m][n] = FZ;

  auto stage = [&](int buf, int k0) {
#pragma unroll
    for (int i = 0; i < 2; i++) {
      int s = i * 256 + tid;
      int row = s >> 2, cc = s & 3;
      int sc = cc ^ (row & 3);
      gl_lds16(A + (size_t)(bm * 128 + row) * K + k0 + sc * 8,
               (char*)&Asm[buf][0] + (i * 256 + (tid & 192)) * 16);
      gl_lds16(Bt + (size_t)(bn * 128 + row) * K + k0 + sc * 8,
               (char*)&Bsm[buf][0] + (i * 256 + (tid & 192)) * 16);
    }
  };

  stage(0, 0);
  __syncthreads();
  for (int t = 0; t < K / 32; t++) {
    int cur = t & 1;
    if (t + 1 < K / 32) stage(cur ^ 1, (t + 1) * 32);
    bh8 a[4], b[4];
#pragma unroll
    for (int m = 0; m < 4; m++) {
      int row = wm * 64 + m * 16 + c15;
      int ch = g ^ (row & 3);
      a[m] = *(const bh8*)((const char*)&Asm[cur][0] + row * 64 + ch * 16);
    }
#pragma unroll
    for (int n = 0; n < 4; n++) {
      int row = wn * 64 + n * 16 + c15;
      int ch = g ^ (row & 3);
      b[n] = *(const bh8*)((const char*)&Bsm[cur][0] + row * 64 + ch * 16);
    }
#pragma unroll
    for (int m = 0; m < 4; m++)
#pragma unroll
      for (int n = 0; n < 4; n++)
        acc[m][n] = __builtin_amdgcn_mfma_f32_16x16x32_bf16(a[m], b[n], acc[m][n], 0, 0, 0);
    __syncthreads();
  }

#pragma unroll
  for (int m = 0; m < 4; m++) {
    int rbase = bm * 128 + wm * 64 + m * 16 + g * 4;
#pragma unroll
    for (int n = 0; n < 4; n++) {
      int col = bn * 128 + wn * 64 + n * 16 + c15;
#pragma unroll
      for (int r = 0; r < 4; r++) {
        int mrow = rbase + r;
        float val = acc[m][n][r];
        if (z <= 1) {
          val = val + bias[col];
          if (z == 0) val *= 0.125f * LOG2E;  // fold 1/sqrt(D) and log2 domain
          int bb = mrow >> 11, ss = mrow & 2047, hh = col >> 6, dd = col & 63;
          Cout[((size_t)(bb * H_ + hh) * S_ + ss) * D_ + dd] = f2bf(val);
        } else {
          val = val + bias[mrow];
          int bb = col >> 11, ss = col & 2047, hh = mrow >> 6, dd = mrow & 63;
          Cout[((size_t)(bb * H_ + hh) * D_ + dd) * S_ + ss] = f2bf(val);
        }
      }
    }
  }
}

// ================= output GEMM: d_out = AO@Wo^T + bo (fp32) =================
__global__ void __launch_bounds__(256)
gemm_out(const ubf* __restrict__ A, const ubf* __restrict__ Bt,
         const float* __restrict__ bias, float* __restrict__ Cout, int N) {
  constexpr int K = 1024;
  __shared__ ubf Asm[2][128 * 32];
  __shared__ ubf Bsm[2][128 * 32];
  const int tid = threadIdx.x;
  const int lane = tid & 63, w = tid >> 6;
  const int wm = w >> 1, wn = w & 1;
  const int bm = blockIdx.y, bn = blockIdx.x;
  const int g = lane >> 4, c15 = lane & 15;

  const fx4 FZ = {0.f, 0.f, 0.f, 0.f};
  fx4 acc[4][4];
#pragma unroll
  for (int m = 0; m < 4; m++)
#pragma unroll
    for (int n = 0; n < 4; n++) acc[m][n] = FZ;

  auto stage = [&](int buf, int k0) {
#pragma unroll
    for (int i = 0; i < 2; i++) {
      int s = i * 256 + tid;
      int row = s >> 2, cc = s & 3;
      int sc = cc ^ (row & 3);
      gl_lds16(A + (size_t)(bm * 128 + row) * K + k0 + sc * 8,
               (char*)&Asm[buf][0] + (i * 256 + (tid & 192)) * 16);
      gl_lds16(Bt + (size_t)(bn * 128 + row) * K + k0 + sc * 8,
               (char*)&Bsm[buf][0] + (i * 256 + (tid & 192)) * 16);
    }
  };

  stage(0, 0);
  __syncthreads();
  for (int t = 0; t < K / 32; t++) {
    int cur = t & 1;
    if (t + 1 < K / 32) stage(cur ^ 1, (t + 1) * 32);
    bh8 a[4], b[4];
#pragma unroll
    for (int m = 0; m < 4; m++) {
      int row = wm * 64 + m * 16 + c15;
      int ch = g ^ (row & 3);
      a[m] = *(const bh8*)((const char*)&Asm[cur][0] + row * 64 + ch * 16);
    }
#pragma unroll
    for (int n = 0; n < 4; n++) {
      int row = wn * 64 + n * 16 + c15;
      int ch = g ^ (row & 3);
      b[n] = *(const bh8*)((const char*)&Bsm[cur][0] + row * 64 + ch * 16);
    }
#pragma unroll
    for (int m = 0; m < 4; m++)
#pragma unroll
      for (int n = 0; n < 4; n++)
        acc[m][n] = __builtin_amdgcn_mfma_f32_16x16x32_bf16(a[m], b[n], acc[m][n], 0, 0, 0);
    __syncthreads();
  }

#pragma unroll
  for (int m = 0; m < 4; m++) {
    int rbase = bm * 128 + wm * 64 + m * 16 + g * 4;
#pragma unroll
    for (int n = 0; n < 4; n++) {
      int col = bn * 128 + wn * 64 + n * 16 + c15;
#pragma unroll
      for (int r = 0; r < 4; r++)
        Cout[(size_t)(rbase + r) * N + col] = acc[m][n][r] + bias[col];
    }
  }
}

// ================= flash attention, KV-split 2-way =================
// Q[B,H,S,D] (pre-scaled by 0.125*LOG2E), K[B,H,S,D], V^T[B,H,D,S]
// -> per-half unnormalized O (fp32) + (m, l) per q-row (log2 domain).
// Swapped QK^T: lane owns q = lane&31 for its 32 scores.
// C/D map (32x32): col=lane&31, row=(r&3)+8*(r>>2)+4*(lane>>5)   [m74/m101]
#define ROWQ(r) (((r) & 3) + 8 * ((r) >> 2) + 4 * hi)

__global__ void __launch_bounds__(256, 4)
flash(const ubf* __restrict__ Q, const ubf* __restrict__ Kh, const ubf* __restrict__ Vt,
      const float* __restrict__ mask, const int* __restrict__ flag,
      float* __restrict__ O0, float* __restrict__ O1, float2* __restrict__ ml) {
  __shared__ ubf Ksm[2][64 * 64];
  __shared__ ubf Vsm[2][64 * 64];
  const int tid = threadIdx.x, lane = tid & 63, w = tid >> 6;
  const int l31 = lane & 31, hi = lane >> 5;
  const int bh = blockIdx.x;   // bh fastest -> XCD locality on K/V
  const int qb = blockIdx.y;   // q-tile (128 rows/block, 32/wave)
  const int half = blockIdx.z;
  const int b = bh >> 4;
  const int use_mask = *flag;
  const int qg = qb * 128 + w * 32 + l31;
  const int k00 = half * (S_ / 2);
  constexpr int NT = (S_ / 2) / 64;  // 16 KV tiles per half

  const ubf* Qrow = Q + ((size_t)bh * S_ + qg) * D_;
  bh8 q4[4];
#pragma unroll
  for (int kf = 0; kf < 4; kf++) q4[kf] = *(const bh8*)(Qrow + kf * 16 + hi * 8);

  fx16 acc0, acc1;
#pragma unroll
  for (int i = 0; i < 16; i++) { acc0[i] = 0.f; acc1[i] = 0.f; }
  float mrun = -3.0e38f, lrun = 0.f;  // log2 domain; lrun is LANE-LOCAL partial

  const ubf* Kg = Kh + (size_t)bh * S_ * D_;
  const ubf* Vg = Vt + (size_t)bh * D_ * S_;

  auto stage = [&](int buf, int k0) {
#pragma unroll
    for (int i = 0; i < 2; i++) {
      int s = i * 256 + tid;
      int row = s >> 3, cc = s & 7;
      int sw = cc ^ (row & 7);  // pre-swizzled global source (rule 21)
      gl_lds16(Kg + (size_t)(k0 + row) * D_ + sw * 8,
               (char*)&Ksm[buf][0] + (i * 256 + (tid & 192)) * 16);
      gl_lds16(Vg + (size_t)row * S_ + k0 + sw * 8,
               (char*)&Vsm[buf][0] + (i * 256 + (tid & 192)) * 16);
    }
  };

  stage(0, k00);
  __syncthreads();

  for (int t = 0; t < NT; t++) {
    int cur = t & 1;
    if (t + 1 < NT) stage(cur ^ 1, k00 + (t + 1) * 64);

    // ---- QK^T: scores[key][q], lane q = l31 (log2 domain)
    fx16 sc0, sc1;
#pragma unroll
    for (int i = 0; i < 16; i++) { sc0[i] = 0.f; sc1[i] = 0.f; }
    __builtin_amdgcn_s_setprio(1);
#pragma unroll
    for (int kf = 0; kf < 4; kf++) {
      {
        int row = l31;
        int ch = (2 * kf + hi) ^ (row & 7);
        bh8 ak = *(const bh8*)((const char*)&Ksm[cur][0] + row * 128 + ch * 16);
        sc0 = __builtin_amdgcn_mfma_f32_32x32x16_bf16(ak, q4[kf], sc0, 0, 0, 0);
      }
      {
        int row = 32 + l31;
        int ch = (2 * kf + hi) ^ (row & 7);
        bh8 ak = *(const bh8*)((const char*)&Ksm[cur][0] + row * 128 + ch * 16);
        sc1 = __builtin_amdgcn_mfma_f32_32x32x16_bf16(ak, q4[kf], sc1, 0, 0, 0);
      }
    }
    __builtin_amdgcn_s_setprio(0);

    if (use_mask) {
      const float* mq = mask + ((size_t)(b * S_ + qg)) * S_ + k00 + t * 64;
#pragma unroll
      for (int r = 0; r < 16; r++) {
        sc0[r] += mq[ROWQ(r)] * (-14426.950408889634f);       // -10000*LOG2E
        sc1[r] += mq[32 + ROWQ(r)] * (-14426.950408889634f);
      }
    }

    // ---- online softmax (log2 domain), tree reductions
    float pm[8];
#pragma unroll
    for (int i = 0; i < 8; i++)
      pm[i] = fmaxf(fmaxf(sc0[2 * i], sc0[2 * i + 1]),
                    fmaxf(sc1[2 * i], sc1[2 * i + 1]));
#pragma unroll
    for (int s = 4; s > 0; s >>= 1)
#pragma unroll
      for (int i = 0; i < 4; i++)
        if (i < s) pm[i] = fmaxf(pm[i], pm[i + s]);
    float pmax = fmaxf(pm[0], __shfl_xor(pm[0], 32));

    if (__any(pmax - mrun > 11.5415603f)) {  // T13 defer-max (8 in ln domain)
      float mnew = fmaxf(mrun, pmax);
      float al = exp2f(mrun - mnew);
      lrun *= al;
#pragma unroll
      for (int r = 0; r < 16; r++) {
        float alr = __shfl(al, ROWQ(r));
        acc0[r] *= alr;
        acc1[r] *= alr;
      }
      mrun = mnew;
    }

    float rsv[4] = {0.f, 0.f, 0.f, 0.f};
#pragma unroll
    for (int i = 0; i < 16; i++) {
      float p0 = exp2f(sc0[i] - mrun);
      float p1 = exp2f(sc1[i] - mrun);
      sc0[i] = p0; sc1[i] = p1;
      rsv[i & 3] += p0 + p1;
    }
    lrun += (rsv[0] + rsv[1]) + (rsv[2] + rsv[3]);  // lane-local; pair-reduce in epilogue

    // ---- pack P to bf16 pairs (T12)
    unsigned pk0[8], pk1[8];
#pragma unroll
    for (int i = 0; i < 8; i++) {
      pk0[i] = cvtpk(sc0[2 * i], sc0[2 * i + 1]);
      pk1[i] = cvtpk(sc1[2 * i], sc1[2 * i + 1]);
    }

    // ---- PV: A = P (row=q=l31), B = V; per kf exchange halves with lane^32
    __builtin_amdgcn_s_setprio(1);
#define PV_STEP(KF, PKN)                                                          \
    {                                                                             \
      const int o = 4 * ((KF) & 1);                                               \
      unsigned x00 = PKN[o], x01 = PKN[o + 1], x10 = PKN[o + 2], x11 = PKN[o + 3];\
      unsigned t0 = hi ? x00 : x10, t1 = hi ? x01 : x11;                          \
      unsigned r0 = (unsigned)__shfl_xor((int)t0, 32);                            \
      unsigned r1 = (unsigned)__shfl_xor((int)t1, 32);                            \
      unsigned wa[4];                                                             \
      wa[0] = hi ? r0 : x00; wa[1] = hi ? r1 : x01;                               \
      wa[2] = hi ? x10 : r0; wa[3] = hi ? x11 : r1;                               \
      bh8 pa = *(bh8*)wa;                                                         \
      {                                                                           \
        int row = l31;                                                            \
        int ch = (2 * (KF) + hi) ^ (row & 7);                                     \
        bh8 bv = *(const bh8*)((const char*)&Vsm[cur][0] + row * 128 + ch * 16);  \
        acc0 = __builtin_amdgcn_mfma_f32_32x32x16_bf16(pa, bv, acc0, 0, 0, 0);    \
      }                                                                           \
      {                                                                           \
        int row = 32 + l31;                                                       \
        int ch = (2 * (KF) + hi) ^ (row & 7);                                     \
        bh8 bv = *(const bh8*)((const char*)&Vsm[cur][0] + row * 128 + ch * 16);  \
        acc1 = __builtin_amdgcn_mfma_f32_32x32x16_bf16(pa, bv, acc1, 0, 0, 0);    \
      }                                                                           \
    }
    PV_STEP(0, pk0)
    PV_STEP(1, pk0)
    PV_STEP(2, pk1)
    PV_STEP(3, pk1)
#undef PV_STEP
    __builtin_amdgcn_s_setprio(0);

    __syncthreads();
  }

  // ---- epilogue: write unnormalized partial O (fp32) + (m, l) per q-row
  float lsum = lrun + __shfl_xor(lrun, 32);
  float* Obase = half ? O1 : O0;
#pragma unroll
  for (int r = 0; r < 16; r++) {
    int q2 = ROWQ(r);
    size_t rowbase = ((size_t)bh * S_ + qb * 128 + w * 32 + q2) * D_;
    Obase[rowbase + l31] = acc0[r];
    Obase[rowbase + 32 + l31] = acc1[r];
  }
  if (hi == 0) {
    int sq = qb * 128 + w * 32 + l31;
    ml[(size_t)half * (32 * S_) + bh * S_ + sq] = make_float2(mrun, lsum);
  }
}

// ================= combine: merge two KV-halves -> AO bf16 [B,S,E] =================
__global__ void __launch_bounds__(256)
combine(const float* __restrict__ O0, const float* __restrict__ O1,
        const float2* __restrict__ ml, ubf* __restrict__ AO) {
  int tid = blockIdx.x * 256 + threadIdx.x;  // 1,048,576 threads
  int row = tid >> 4, dq = tid & 15;         // row = bh*S + s ; 4 d's per thread
  int bh = row >> 11, s = row & 2047;
  float2 m0 = ml[row];
  float2 m1 = ml[32 * S_ + row];
  float m = fmaxf(m0.x, m1.x);
  float w0 = exp2f(m0.x - m), w1 = exp2f(m1.x - m);
  float inv = 1.0f / (m0.y * w0 + m1.y * w1);
  float4 a = *(const float4*)(O0 + (size_t)row * D_ + dq * 4);
  float4 c = *(const float4*)(O1 + (size_t)row * D_ + dq * 4);
  ushort4 o;
  o.x = f2bf((a.x * w0 + c.x * w1) * inv);
  o.y = f2bf((a.y * w0 + c.y * w1) * inv);
  o.z = f2bf((a.z * w0 + c.z * w1) * inv);
  o.w = f2bf((a.w * w0 + c.w * w1) * inv);
  int b_ = bh >> 4, h = bh & 15;
  *(ushort4*)(AO + ((size_t)(b_ * S_ + s)) * E_ + h * 64 + dq * 4) = o;
}

extern "C" void kernel_launch(void* const* d_in, const int* in_sizes, int n_in,
                              void* d_out, int out_size, void* d_ws, size_t ws_size,
                              hipStream_t stream) {
  (void)in_sizes; (void)n_in; (void)out_size; (void)ws_size;
  const float* q  = (const float*)d_in[0];
  const float* k  = (const float*)d_in[1];
  const float* v  = (const float*)d_in[2];
  const float* mask = (const float*)d_in[3];
  const float* Wq = (const float*)d_in[4];
  const float* bq = (const float*)d_in[5];
  const float* Wk = (const float*)d_in[6];
  const float* bk = (const float*)d_in[7];
  const float* Wv = (const float*)d_in[8];
  const float* bv = (const float*)d_in[9];
  const float* Wo = (const float*)d_in[10];
  const float* bo = (const float*)d_in[11];

  char* ws = (char*)d_ws;
  // Phase 1 (prepass/GEMM): X at 0..24MB, Wt0 24..32MB, Qh/Kh/Vt 32..56MB.
  // Phase 2 (flash/combine): X region is dead -> O0 partial (16MB) + ml (1MB);
  //   O1 partial lives in d_out (16MB fp32, fully overwritten by gemm_out later).
  ubf* X    = (ubf*)(ws);
  ubf* Wt0  = (ubf*)(ws + 25165824);
  ubf* Qh   = (ubf*)(ws + 33554432);
  ubf* Kh   = (ubf*)(ws + 41943040);
  ubf* Vt   = (ubf*)(ws + 50331648);
  ubf* AO   = (ubf*)(ws + 58720256);
  int* flag = (int*)(ws + 67108864);
  float*  O0p = (float*)(ws);             // 16 MiB (overlaps dead X)
  float2* mlp = (float2*)(ws + 16777216); // 1 MiB
  float*  O1p = (float*)d_out;            // 16 MiB scratch, overwritten by gemm_out

  ubf* Wot = Wt0 + 3145728;

  cvt3<<<dim3(512, 1, 3), 256, 0, stream>>>(q, k, v, X, flag);
  wtrans4<<<dim3(32, 32, 4), 256, 0, stream>>>(Wq, Wk, Wv, Wo, Wt0);
  maskscan<<<1024, 256, 0, stream>>>(mask, (B_ * S_ * S_) / 4, flag);

  gemm_qkv<<<dim3(32, 8, 3), 256, 0, stream>>>(X, Wt0, bq, bk, bv, Qh);

  flash<<<dim3(32, 16, 2), 256, 0, stream>>>(Qh, Kh, Vt, mask, flag, O0p, O1p, mlp);
  combine<<<4096, 256, 0, stream>>>(O0p, O1p, mlp, AO);

  gemm_out<<<dim3(8, 32), 256, 0, stream>>>(AO, Wot, bo, (float*)d_out, 1024);
}